// Round 3
// baseline (296.073 us; speedup 1.0000x reference)
//
#include <hip/hip_runtime.h>
#include <hip/hip_bf16.h>

typedef __attribute__((ext_vector_type(8))) short bf16x8;  // 8 bf16 = 4 VGPRs
typedef __attribute__((ext_vector_type(4))) float f32x4;   // MFMA C/D
typedef __attribute__((ext_vector_type(4))) int   i32x4;

#define BIGC 10000.0f
#define TPW 2          // macro-iterations (64 points per wave each)
#define WAVES 4

__device__ __forceinline__ float fast_exp2(float x) { return __builtin_amdgcn_exp2f(x); }
__device__ __forceinline__ float fast_log2(float x) { return __builtin_amdgcn_logf(x); }
__device__ __forceinline__ float fast_rcp(float x)  { return __builtin_amdgcn_rcpf(x); }

__device__ __forceinline__ float fast_tanh(float x) {
    const float ax = fabsf(x);
    const float e  = fast_exp2(ax * 2.8853900817779268f);   // e^(2|x|)
    const float r  = 1.0f - 2.0f * fast_rcp(e + 1.0f);
    return copysignf(r, x);
}
// softplus(v) + 1e-4, applied post-transpose to the 10 real features only.
__device__ __forceinline__ float fast_softplus_eps(float v) {
    const float e = fast_exp2(fabsf(v) * -1.4426950408889634f);  // exp(-|v|)
    const float l = fast_log2(1.0f + e) * 0.6931471805599453f;   // ln(1+e)
    return fmaxf(v, 0.0f) + l + 0.0001f;
}
// Pack two f32 -> two bf16 (RNE) in ONE instruction.
__device__ __forceinline__ unsigned pack2bf(float hi, float lo) {
    unsigned r;
    asm("v_cvt_pk_bf16_f32 %0, %1, %2" : "=v"(r) : "v"(lo), "v"(hi));
    return r;
}

// MFMA 16x16x32 layouts (verified in earlier rounds):
//   A: lane holds A[m=lane&15][k=(lane>>4)*8+j]
//   B: lane holds B[k=(lane>>4)*8+j][n=lane&15]
//   C/D: lane holds D[row=(lane>>4)*4+reg][col=lane&15]
//
// GEMM1 TRANSPOSED: h^T(64x16) = W1'^T(64x19) @ z^T(19x16), 4 M-tiles (a).
//   z k-slots: k<16 -> t_feat[k]; k=16 -> tanh(x0); k=17 -> tanh(x1);
//              k=18 -> 1.0 (bias row, A value = b1); k>18 -> 0.
// GEMM2 NORMAL: d(16x10) = h(16x64) @ W2sig(64x10); sigma K-permutation folded
//   into W2 row order so A-frag comes from SAME-LANE relu(acc) repack (no LDS).
//
// R3 thesis: TLP over ILP. R2 proved the compiler re-serializes source-level
// ILP schedules (VGPR 72, occupancy 25%, dur flat). This round: serial-subtile
// body (fits 48 VGPR), hard VGPR cap 64 via launch_bounds(256,8) to restore
// the 8-waves/SIMD occupancy step, TPW=2 (grid 4096) for smoother residency,
// and softplus moved AFTER the LDS transpose (10 real features per lane
// instead of 16 padded ones — numerically identical, shorter B5 chain).
__global__ void __launch_bounds__(256, 8) coupling_mfma6(
    const float* __restrict__ x, const float* __restrict__ t_feat,
    const float* __restrict__ mask, const float* __restrict__ W1,
    const float* __restrict__ b1, const float* __restrict__ W2,
    const float* __restrict__ b2, float* __restrict__ out, int n)
{
    // Only d needs LDS (feat index must move across lanes for interp).
    // Wave-private; stride 11 dwords (gcd(11,32)=1 -> 2-way max = free).
    __shared__ float lds_d[WAVES][64][11];

    const int wave = threadIdx.x >> 6;
    const int lane = threadIdx.x & 63;
    const int m    = lane & 15;
    const int q    = lane >> 4;
    const int m4   = m << 2;

    // ---- constant fragments (built once, resident in VGPRs) ----
    bf16x8 w1f[4];   // GEMM1 A-frags: lane (q,m) elem j = W1row(sigma_z(8q+j))[16a+m]
#pragma unroll
    for (int a = 0; a < 4; ++a) {
        float wv[8];
#pragma unroll
        for (int j = 0; j < 8; ++j) {
            const int k = q * 8 + j;
            const int col = 16 * a + m;
            float v = 0.0f;
            if (k < 16)       v = W1[(k + 2) * 64 + col];
            else if (k == 16) v = W1[0 * 64 + col];
            else if (k == 17) v = W1[1 * 64 + col];
            else if (k == 18) v = b1[col];          // bias folded in
            wv[j] = v;
        }
        i32x4 f = { (int)pack2bf(wv[1], wv[0]), (int)pack2bf(wv[3], wv[2]),
                    (int)pack2bf(wv[5], wv[4]), (int)pack2bf(wv[7], wv[6]) };
        w1f[a] = __builtin_bit_cast(bf16x8, f);
    }
    bf16x8 w2f[2];   // GEMM2 B-frags with sigma row-permutation
#pragma unroll
    for (int fi = 0; fi < 2; ++fi) {
        float wv[8];
#pragma unroll
        for (int j = 0; j < 8; ++j) {
            const int hid = 32 * fi + 16 * (j >> 2) + 4 * q + (j & 3);
            wv[j] = (m < 10) ? W2[hid * 10 + m] : 0.0f;
        }
        i32x4 f = { (int)pack2bf(wv[1], wv[0]), (int)pack2bf(wv[3], wv[2]),
                    (int)pack2bf(wv[5], wv[4]), (int)pack2bf(wv[7], wv[6]) };
        w2f[fi] = __builtin_bit_cast(bf16x8, f);
    }
    const float bias2 = (m < 10) ? b2[m] : 0.0f;
    const float m0 = mask[0], m1 = mask[1];

    for (int it = 0; it < TPW; ++it) {
        // Wave-uniform base, clamped so the full 64-point tile is in-bounds
        // (tail points recomputed by multiple waves with identical values —
        //  benign; assumes n >= 64, true here).
        int pb = (blockIdx.x * TPW + it) * (WAVES * 64) + wave * 64;
        pb = max(min(pb, n - 64), 0);

        // ==== phase A: issue all global loads for this iteration ====
        const int pl = pb + lane;
        const float* xp = x + pl * 3;
        const float xi0 = xp[0], xi1 = xp[1], xi2 = xp[2];

        float4 ta[4], tb[4];
        if (q < 2) {
#pragma unroll
            for (int s = 0; s < 4; ++s) {
                const float4* tr = (const float4*)(t_feat + (pb + 16 * s + m) * 16 + q * 8);
                ta[s] = tr[0];
                tb[s] = tr[1];
            }
        }

        // tanh once per lane on its own point; z-frags pull via bpermute.
        const unsigned pk = pack2bf(fast_tanh(xi1), fast_tanh(xi0));

        // ==== phase B: 4 sub-tiles of 16 points (serial — TLP hides latency) ====
#pragma unroll
        for (int s = 0; s < 4; ++s) {
            // lane (q=2,m) needs point pb+16s+m -> lives in lane 16s+m
            const int tp = __builtin_amdgcn_ds_bpermute(s * 64 + m4, (int)pk);

            i32x4 zw = { 0, 0, 0, 0 };
            if (q < 2) {
                zw[0] = (int)pack2bf(ta[s].y, ta[s].x);
                zw[1] = (int)pack2bf(ta[s].w, ta[s].z);
                zw[2] = (int)pack2bf(tb[s].y, tb[s].x);
                zw[3] = (int)pack2bf(tb[s].w, tb[s].z);
            } else if (q == 2) {
                zw[0] = tp;                        // [tanh(x1)|tanh(x0)]
                zw[1] = 0x3F80;                    // k=18: bf16(1.0) bias slot
            }
            const bf16x8 zf = __builtin_bit_cast(bf16x8, zw);

            // ---- GEMM1 (transposed): 4 independent MFMAs, bias folded ----
            f32x4 acc[4];
#pragma unroll
            for (int a = 0; a < 4; ++a) {
                f32x4 c = { 0.0f, 0.0f, 0.0f, 0.0f };
                acc[a] = __builtin_amdgcn_mfma_f32_16x16x32_bf16(w1f[a], zf, c, 0, 0, 0);
            }

            // ---- relu + IN-LANE repack to GEMM2 A-frags (no LDS!) ----
            float rl[16];
#pragma unroll
            for (int a = 0; a < 4; ++a)
#pragma unroll
                for (int r = 0; r < 4; ++r)
                    rl[4 * a + r] = fmaxf(acc[a][r], 0.0f);
            i32x4 a20 = { (int)pack2bf(rl[1],  rl[0]),  (int)pack2bf(rl[3],  rl[2]),
                          (int)pack2bf(rl[5],  rl[4]),  (int)pack2bf(rl[7],  rl[6]) };
            i32x4 a21 = { (int)pack2bf(rl[9],  rl[8]),  (int)pack2bf(rl[11], rl[10]),
                          (int)pack2bf(rl[13], rl[12]), (int)pack2bf(rl[15], rl[14]) };

            // ---- GEMM2: two INDEPENDENT MFMAs, summed after ----
            f32x4 cb = { bias2, bias2, bias2, bias2 };
            f32x4 cz = { 0.0f, 0.0f, 0.0f, 0.0f };
            f32x4 cd0 = __builtin_amdgcn_mfma_f32_16x16x32_bf16(
                            __builtin_bit_cast(bf16x8, a20), w2f[0], cb, 0, 0, 0);
            f32x4 cd1 = __builtin_amdgcn_mfma_f32_16x16x32_bf16(
                            __builtin_bit_cast(bf16x8, a21), w2f[1], cz, 0, 0, 0);

            // ---- RAW d to LDS (softplus deferred to phase C) ----
#pragma unroll
            for (int r = 0; r < 4; ++r) {
                const float dv = cd0[r] + cd1[r];
                if (m < 10) lds_d[wave][16 * s + 4 * q + r][m] = dv;
            }
        }

        // ==== phase C: softplus + interp + store, one point per lane ====
        {
            const float* dd = lds_d[wave][lane];
            const float dxl2 = fast_softplus_eps(dd[0]);
            const float dxl1 = fast_softplus_eps(dd[1]);
            const float dxr1 = fast_softplus_eps(dd[2]);
            const float dxr2 = fast_softplus_eps(dd[3]);
            const float dyl2 = fast_softplus_eps(dd[4]);
            const float dyl1 = fast_softplus_eps(dd[5]);
            const float dyr1 = fast_softplus_eps(dd[6]);
            const float dyr2 = fast_softplus_eps(dd[7]);
            const float kl = fast_softplus_eps(dd[8]) * 2.0f;
            const float kr = fast_softplus_eps(dd[9]) * 2.0f;

            const float xL1 = -dxl1,        yL1 = -dyl1;
            const float xL2 = -dxl1 - dxl2, yL2 = -dyl1 - dyl2;
            const float xR1 = dxr1,         yR1 = dyr1;
            const float xR2 = dxr1 + dxr2,  yR2 = dyr1 + dyr2;
            const float xR3 = xR2 + BIGC,   yR3 = fmaf(kr, BIGC, yR2);
            const float xL3 = xL2 - BIGC,   yL3 = fmaf(-kl, BIGC, yL2);

            float qx = fminf(fmaxf(xi2, xL3 * 0.99f), xR3 * 0.99f);
            float xl = xL3, xrr = xL2, yl = yL3, yr = yL2;
            if (qx >= xL2) { xl = xL2; xrr = xL1; yl = yL2; yr = yL1; }
            if (qx >= xL1) { xl = xL1; xrr = xR1; yl = yL1; yr = yR1; }
            if (qx >= xR1) { xl = xR1; xrr = xR2; yl = yR1; yr = yR2; }
            if (qx >= xR2) { xl = xR2; xrr = xR3; yl = yR2; yr = yR3; }
            const float slope = (yr - yl) * fast_rcp(xrr - xl);
            const float res = fmaf(slope, qx - xl, yl);

            // pb-clamped => always in-bounds; tail duplicates write identical
            // values from different waves — benign.
            float* op = out + pl * 3;
            op[0] = xi0 * m0;
            op[1] = xi1 * m1;
            op[2] = res;
        }
    }
}

extern "C" void kernel_launch(void* const* d_in, const int* in_sizes, int n_in,
                              void* d_out, int out_size, void* d_ws, size_t ws_size,
                              hipStream_t stream) {
    const float* x      = (const float*)d_in[0];
    const float* t_feat = (const float*)d_in[1];
    const float* mask   = (const float*)d_in[2];
    const float* W1     = (const float*)d_in[3];
    const float* b1     = (const float*)d_in[4];
    const float* W2     = (const float*)d_in[5];
    const float* b2     = (const float*)d_in[6];
    float* out = (float*)d_out;

    const int n = in_sizes[0] / 3;                       // 2097152 points
    const int pts_per_block = TPW * WAVES * 64;          // 512
    const int grid = (n + pts_per_block - 1) / pts_per_block;   // 4096
    coupling_mfma6<<<grid, 256, 0, stream>>>(x, t_feat, mask, W1, b1, W2, b2, out, n);
}

// Round 4
// 233.043 us; speedup vs baseline: 1.2705x; 1.2705x over previous
//
#include <hip/hip_runtime.h>
#include <hip/hip_bf16.h>

typedef __attribute__((ext_vector_type(8))) short bf16x8;  // 8 bf16 = 4 VGPRs
typedef __attribute__((ext_vector_type(4))) float f32x4;   // MFMA C/D
typedef __attribute__((ext_vector_type(4))) int   i32x4;

#define BIGC 10000.0f
#define TPW 4          // macro-iterations (64 points per wave each)
#define WAVES 4

__device__ __forceinline__ float fast_exp2(float x) { return __builtin_amdgcn_exp2f(x); }
__device__ __forceinline__ float fast_log2(float x) { return __builtin_amdgcn_logf(x); }
__device__ __forceinline__ float fast_rcp(float x)  { return __builtin_amdgcn_rcpf(x); }

__device__ __forceinline__ float fast_tanh(float x) {
    const float ax = fabsf(x);
    const float e  = fast_exp2(ax * 2.8853900817779268f);   // e^(2|x|)
    const float r  = 1.0f - 2.0f * fast_rcp(e + 1.0f);
    return copysignf(r, x);
}
// softplus(v) + 1e-4, applied post-transpose to the 10 real features only
// (verified numerically identical in R3: same absmax as in-B5 softplus).
__device__ __forceinline__ float fast_softplus_eps(float v) {
    const float e = fast_exp2(fabsf(v) * -1.4426950408889634f);  // exp(-|v|)
    const float l = fast_log2(1.0f + e) * 0.6931471805599453f;   // ln(1+e)
    return fmaxf(v, 0.0f) + l + 0.0001f;
}
// Pack two f32 -> two bf16 (RNE) in ONE instruction.
__device__ __forceinline__ unsigned pack2bf(float hi, float lo) {
    unsigned r;
    asm("v_cvt_pk_bf16_f32 %0, %1, %2" : "=v"(r) : "v"(lo), "v"(hi));
    return r;
}

// MFMA 16x16x32 layouts (verified in earlier rounds):
//   A: lane holds A[m=lane&15][k=(lane>>4)*8+j]
//   B: lane holds B[k=(lane>>4)*8+j][n=lane&15]
//   C/D: lane holds D[row=(lane>>4)*4+reg][col=lane&15]
//
// GEMM1 TRANSPOSED: h^T(64x16) = W1'^T(64x19) @ z^T(19x16), 4 M-tiles (a).
//   z k-slots: k<16 -> t_feat[k]; k=16 -> tanh(x0); k=17 -> tanh(x1);
//              k=18 -> 1.0 (bias row, A value = b1); k>18 -> 0.
// GEMM2 NORMAL: d(16x10) = h(16x64) @ W2sig(64x10); sigma K-permutation folded
//   into W2 row order so A-frag comes from SAME-LANE relu(acc) repack (no LDS).
//
// R4: revert to the proven R1 skeleton (80 us, 48 VGPR, launch_bounds(256,4)
// -- R3's (256,8) cap caused scratch spills: WRITE_SIZE 24.5->342 MB, +87%
// dur). Keep ONLY R3's verified-safe deferred softplus (10 real values in
// phase C instead of 16 padded in B5, ~-100 VALU+trans/iter). Plus a
// wave-uniform s_sleep stagger ramp at entry (0..~900 cyc) to de-phase the
// lockstep load/VALU bursts across resident waves (convoy hypothesis H2):
// if real, VALUBusy rises >=40% and dur drops below 68 us.
__global__ void __launch_bounds__(256, 4) coupling_mfma7(
    const float* __restrict__ x, const float* __restrict__ t_feat,
    const float* __restrict__ mask, const float* __restrict__ W1,
    const float* __restrict__ b1, const float* __restrict__ W2,
    const float* __restrict__ b2, float* __restrict__ out, int n)
{
    // Only d needs LDS (feat index must move across lanes for interp).
    // Wave-private; stride 11 dwords (gcd(11,32)=1 -> 2-way max = free).
    __shared__ float lds_d[WAVES][64][11];

    const int wave = threadIdx.x >> 6;
    const int lane = threadIdx.x & 63;
    const int m    = lane & 15;
    const int q    = lane >> 4;
    const int m4   = m << 2;

    // ---- convoy de-phaser: wave-uniform staggered start (H2 probe) ----
    // s_sleep needs an immediate -> runtime-count loop of s_sleep(1) (~64 cyc
    // each). Stagger 0..14 units (~0-900 cyc), keyed on wave + block parity.
    {
        const int stag = (((blockIdx.x & 1) << 2) | wave) * 2;
        for (int i = 0; i < stag; ++i) __builtin_amdgcn_s_sleep(1);
    }

    // ---- constant fragments (built once, resident in VGPRs) ----
    bf16x8 w1f[4];   // GEMM1 A-frags: lane (q,m) elem j = W1row(sigma_z(8q+j))[16a+m]
#pragma unroll
    for (int a = 0; a < 4; ++a) {
        float wv[8];
#pragma unroll
        for (int j = 0; j < 8; ++j) {
            const int k = q * 8 + j;
            const int col = 16 * a + m;
            float v = 0.0f;
            if (k < 16)       v = W1[(k + 2) * 64 + col];
            else if (k == 16) v = W1[0 * 64 + col];
            else if (k == 17) v = W1[1 * 64 + col];
            else if (k == 18) v = b1[col];          // bias folded in
            wv[j] = v;
        }
        i32x4 f = { (int)pack2bf(wv[1], wv[0]), (int)pack2bf(wv[3], wv[2]),
                    (int)pack2bf(wv[5], wv[4]), (int)pack2bf(wv[7], wv[6]) };
        w1f[a] = __builtin_bit_cast(bf16x8, f);
    }
    bf16x8 w2f[2];   // GEMM2 B-frags with sigma row-permutation
#pragma unroll
    for (int fi = 0; fi < 2; ++fi) {
        float wv[8];
#pragma unroll
        for (int j = 0; j < 8; ++j) {
            const int hid = 32 * fi + 16 * (j >> 2) + 4 * q + (j & 3);
            wv[j] = (m < 10) ? W2[hid * 10 + m] : 0.0f;
        }
        i32x4 f = { (int)pack2bf(wv[1], wv[0]), (int)pack2bf(wv[3], wv[2]),
                    (int)pack2bf(wv[5], wv[4]), (int)pack2bf(wv[7], wv[6]) };
        w2f[fi] = __builtin_bit_cast(bf16x8, f);
    }
    const float bias2 = (m < 10) ? b2[m] : 0.0f;
    const float m0 = mask[0], m1 = mask[1];

    for (int it = 0; it < TPW; ++it) {
        // Wave-uniform base, clamped so the full 64-point tile is in-bounds
        // (n = 2^21 is a multiple of the tile here, so clamps are inactive;
        //  kept for safety — SALU-cheap on uniform pb).
        int pb = (blockIdx.x * TPW + it) * (WAVES * 64) + wave * 64;
        pb = max(min(pb, n - 64), 0);

        // ==== phase A: issue all global loads for this iteration ====
        const int pl = pb + lane;
        const float* xp = x + pl * 3;
        const float xi0 = xp[0], xi1 = xp[1], xi2 = xp[2];

        float4 ta[4], tb[4];
        if (q < 2) {
#pragma unroll
            for (int s = 0; s < 4; ++s) {
                const float4* tr = (const float4*)(t_feat + (pb + 16 * s + m) * 16 + q * 8);
                ta[s] = tr[0];
                tb[s] = tr[1];
            }
        }

        // tanh once per lane on its own point; z-frags pull via bpermute.
        const unsigned pk = pack2bf(fast_tanh(xi1), fast_tanh(xi0));

        // ==== phase B: 4 sub-tiles of 16 points ====
#pragma unroll
        for (int s = 0; s < 4; ++s) {
            // lane (q=2,m) needs point pb+16s+m -> lives in lane 16s+m
            const int tp = __builtin_amdgcn_ds_bpermute(s * 64 + m4, (int)pk);

            i32x4 zw = { 0, 0, 0, 0 };
            if (q < 2) {
                zw[0] = (int)pack2bf(ta[s].y, ta[s].x);
                zw[1] = (int)pack2bf(ta[s].w, ta[s].z);
                zw[2] = (int)pack2bf(tb[s].y, tb[s].x);
                zw[3] = (int)pack2bf(tb[s].w, tb[s].z);
            } else if (q == 2) {
                zw[0] = tp;                        // [tanh(x1)|tanh(x0)]
                zw[1] = 0x3F80;                    // k=18: bf16(1.0) bias slot
            }
            const bf16x8 zf = __builtin_bit_cast(bf16x8, zw);

            // ---- GEMM1 (transposed): 4 independent MFMAs, bias folded ----
            f32x4 acc[4];
#pragma unroll
            for (int a = 0; a < 4; ++a) {
                f32x4 c = { 0.0f, 0.0f, 0.0f, 0.0f };
                acc[a] = __builtin_amdgcn_mfma_f32_16x16x32_bf16(w1f[a], zf, c, 0, 0, 0);
            }

            // ---- relu + IN-LANE repack to GEMM2 A-frags (no LDS!) ----
            float rl[16];
#pragma unroll
            for (int a = 0; a < 4; ++a)
#pragma unroll
                for (int r = 0; r < 4; ++r)
                    rl[4 * a + r] = fmaxf(acc[a][r], 0.0f);
            i32x4 a20 = { (int)pack2bf(rl[1],  rl[0]),  (int)pack2bf(rl[3],  rl[2]),
                          (int)pack2bf(rl[5],  rl[4]),  (int)pack2bf(rl[7],  rl[6]) };
            i32x4 a21 = { (int)pack2bf(rl[9],  rl[8]),  (int)pack2bf(rl[11], rl[10]),
                          (int)pack2bf(rl[13], rl[12]), (int)pack2bf(rl[15], rl[14]) };

            // ---- GEMM2: two INDEPENDENT MFMAs, summed after ----
            f32x4 cb = { bias2, bias2, bias2, bias2 };
            f32x4 cz = { 0.0f, 0.0f, 0.0f, 0.0f };
            f32x4 cd0 = __builtin_amdgcn_mfma_f32_16x16x32_bf16(
                            __builtin_bit_cast(bf16x8, a20), w2f[0], cb, 0, 0, 0);
            f32x4 cd1 = __builtin_amdgcn_mfma_f32_16x16x32_bf16(
                            __builtin_bit_cast(bf16x8, a21), w2f[1], cz, 0, 0, 0);

            // ---- RAW d to LDS (softplus deferred to phase C) ----
#pragma unroll
            for (int r = 0; r < 4; ++r) {
                const float dv = cd0[r] + cd1[r];
                if (m < 10) lds_d[wave][16 * s + 4 * q + r][m] = dv;
            }
        }

        // ==== phase C: softplus + interp + store, one point per lane ====
        {
            const float* dd = lds_d[wave][lane];
            const float dxl2 = fast_softplus_eps(dd[0]);
            const float dxl1 = fast_softplus_eps(dd[1]);
            const float dxr1 = fast_softplus_eps(dd[2]);
            const float dxr2 = fast_softplus_eps(dd[3]);
            const float dyl2 = fast_softplus_eps(dd[4]);
            const float dyl1 = fast_softplus_eps(dd[5]);
            const float dyr1 = fast_softplus_eps(dd[6]);
            const float dyr2 = fast_softplus_eps(dd[7]);
            const float kl = fast_softplus_eps(dd[8]) * 2.0f;
            const float kr = fast_softplus_eps(dd[9]) * 2.0f;

            const float xL1 = -dxl1,        yL1 = -dyl1;
            const float xL2 = -dxl1 - dxl2, yL2 = -dyl1 - dyl2;
            const float xR1 = dxr1,         yR1 = dyr1;
            const float xR2 = dxr1 + dxr2,  yR2 = dyr1 + dyr2;
            const float xR3 = xR2 + BIGC,   yR3 = fmaf(kr, BIGC, yR2);
            const float xL3 = xL2 - BIGC,   yL3 = fmaf(-kl, BIGC, yL2);

            float qx = fminf(fmaxf(xi2, xL3 * 0.99f), xR3 * 0.99f);
            float xl = xL3, xrr = xL2, yl = yL3, yr = yL2;
            if (qx >= xL2) { xl = xL2; xrr = xL1; yl = yL2; yr = yL1; }
            if (qx >= xL1) { xl = xL1; xrr = xR1; yl = yL1; yr = yR1; }
            if (qx >= xR1) { xl = xR1; xrr = xR2; yl = yR1; yr = yR2; }
            if (qx >= xR2) { xl = xR2; xrr = xR3; yl = yR2; yr = yR3; }
            const float slope = (yr - yl) * fast_rcp(xrr - xl);
            const float res = fmaf(slope, qx - xl, yl);

            // pb-clamped => always in-bounds; tail duplicates (inactive for
            // this n) would write identical values — benign.
            float* op = out + pl * 3;
            op[0] = xi0 * m0;
            op[1] = xi1 * m1;
            op[2] = res;
        }
    }
}

extern "C" void kernel_launch(void* const* d_in, const int* in_sizes, int n_in,
                              void* d_out, int out_size, void* d_ws, size_t ws_size,
                              hipStream_t stream) {
    const float* x      = (const float*)d_in[0];
    const float* t_feat = (const float*)d_in[1];
    const float* mask   = (const float*)d_in[2];
    const float* W1     = (const float*)d_in[3];
    const float* b1     = (const float*)d_in[4];
    const float* W2     = (const float*)d_in[5];
    const float* b2     = (const float*)d_in[6];
    float* out = (float*)d_out;

    const int n = in_sizes[0] / 3;                       // 2097152 points
    const int pts_per_block = TPW * WAVES * 64;          // 1024
    const int grid = (n + pts_per_block - 1) / pts_per_block;   // 2048
    coupling_mfma7<<<grid, 256, 0, stream>>>(x, t_feat, mask, W1, b1, W2, b2, out, n);
}